// Round 3
// baseline (5438.797 us; speedup 1.0000x reference)
//
#include <hip/hip_runtime.h>
#include <hip/hip_bf16.h>

// LSTM forward: T=512 (511 steps), B=1024, I=128, H=256, 4H=1024.
// Round 3: 256 wgs = 64 batch groups x 4 hidden slices. W_hh slice (128 KB)
// LDS-resident; W_ih slice (32 VGPRs) register-resident; h exchanged as bf16
// via global memory with relaxed-RMW polling (no per-poll L2 invalidate).
// x A-frags and next-step x-part GEMM overlap the sync window.

#define T_STEPS 511
#define BATCH   1024
#define IN      128
#define HID     256
#define NG      1024
#define KTOT    384
#define BWG     16
#define NGROUP  64
#define NSLICE  4
#define SW      264   // LDS W_hh row stride (bf16), 16B-aligned

typedef __bf16 bf16x8 __attribute__((ext_vector_type(8)));
typedef float  f32x4  __attribute__((ext_vector_type(4)));

// workspace layout (bytes)
#define WCAT_OFF 0
#define BIAS_OFF 786432
#define HEXG_OFF 790528                 // 2*64*16*256 bf16 = 1 MB
#define CNT_OFF  1839104                // 64 groups * 32 ints

__global__ void precast_kernel(const float* __restrict__ W_ih,
                               const float* __restrict__ W_hh,
                               const float* __restrict__ b_ih,
                               const float* __restrict__ b_hh,
                               __bf16* __restrict__ wcat,
                               float* __restrict__ bias,
                               int* __restrict__ cnt) {
    int idx = blockIdx.x * blockDim.x + threadIdx.x;
    if (idx < NG * KTOT) {
        int n = idx / KTOT, k = idx % KTOT;
        float v = (k < IN) ? W_ih[n * IN + k] : W_hh[n * HID + (k - IN)];
        wcat[idx] = (__bf16)v;
    }
    if (idx < NG) bias[idx] = b_ih[idx] + b_hh[idx];
    if (idx < NGROUP * 32) cnt[idx] = 0;
}

__device__ __forceinline__ float sigmoidf_fast(float v) {
    return 1.f / (1.f + __expf(-v));
}
__device__ __forceinline__ float tanhf_fast(float v) {
    return 1.f - 2.f / (1.f + __expf(2.f * v));
}

#define MFMA(a, b, c) __builtin_amdgcn_mfma_f32_16x16x32_bf16((a), (b), (c), 0, 0, 0)

__device__ __forceinline__ bf16x8 cvt_pack(float4 lo, float4 hi) {
    return bf16x8{(__bf16)lo.x, (__bf16)lo.y, (__bf16)lo.z, (__bf16)lo.w,
                  (__bf16)hi.x, (__bf16)hi.y, (__bf16)hi.z, (__bf16)hi.w};
}

__global__ __launch_bounds__(512, 2) void lstm_kernel(
    const float* __restrict__ x,      // (512,1024,128) fp32
    const __bf16* __restrict__ wcat,  // (1024,384) bf16
    const float* __restrict__ bias,   // (1024,)
    const float* __restrict__ hx0,
    const float* __restrict__ cx0,
    __bf16* __restrict__ hexg,        // [2][64][16][256] bf16
    int* __restrict__ cnt,            // [64][32] int
    float* __restrict__ out)          // h (1024,256), c (1024,256) fp32
{
    __shared__ alignas(16) __bf16 Whh[256 * SW];   // 135168 B

    const int tid  = threadIdx.x;
    const int bx   = blockIdx.x;
    // partners of a group differ only in bits 3..4 -> same (bx % 8) -> same XCD
    const int g    = (bx & 7) | ((bx >> 5) << 3);  // batch group 0..63
    const int s    = (bx >> 3) & 3;                // hidden slice 0..3
    const int wave = tid >> 6;
    const int lane = tid & 63;
    const int col  = lane & 15;
    const int quad = lane >> 4;
    const int hf   = col >> 3;        // 0: {i,g} lanes, 1: {f,o} lanes
    const int b0   = g * BWG;
    const int j0   = s * 64;
    const int jcol = j0 + wave * 8 + (col & 7);

    int* cntg = cnt + g * 32;

    // ---- fill LDS W_hh: row r = gate(r>>6), hidden col j0+(r&63), k=0..255 ----
    {
        int r  = tid >> 1;
        int hh = (tid & 1) * 128;
        int ngl = ((r >> 6) << 8) + j0 + (r & 63);
        const __bf16* src = wcat + (size_t)ngl * KTOT + IN + hh;
        __bf16* dst = &Whh[r * SW + hh];
        #pragma unroll
        for (int i = 0; i < 16; ++i)
            *(bf16x8*)(dst + i * 8) = *(const bf16x8*)(src + i * 8);
    }

    // ---- W_ih fragments in registers: tile0 {i|f}, tile1 {g|o} ----
    const int n0 = (hf ? 256 : 0) + jcol;
    const int n1 = 512 + (hf ? 256 : 0) + jcol;
    bf16x8 wi0[4], wi1[4];
    #pragma unroll
    for (int ks = 0; ks < 4; ++ks) {
        wi0[ks] = *(const bf16x8*)(wcat + (size_t)n0 * KTOT + ks * 32 + quad * 8);
        wi1[ks] = *(const bf16x8*)(wcat + (size_t)n1 * KTOT + ks * 32 + quad * 8);
    }

    const float bi  = bias[jcol];
    const float bfv = bias[256 + jcol];
    const float bg  = bias[512 + jcol];
    const float bo  = bias[768 + jcol];

    float cst[4], hn[4];
    {
        float cv = cx0[jcol];
        #pragma unroll
        for (int r = 0; r < 4; ++r) cst[r] = cv;
    }

    // ---- x prefetch for t=0 ----
    float4 xf[8];
    #pragma unroll
    for (int ks = 0; ks < 4; ++ks) {
        const float* xp = x + (size_t)(b0 + col) * IN + ks * 32 + quad * 8;
        xf[2 * ks]     = *(const float4*)xp;
        xf[2 * ks + 1] = *(const float4*)(xp + 4);
    }

    // LDS B-frag base pointers
    const int nl0 = hf * 64 + wave * 8 + (col & 7);
    const __bf16* wl0 = &Whh[nl0 * SW + quad * 8];
    const __bf16* wl1 = &Whh[(128 + nl0) * SW + quad * 8];

    __syncthreads();   // Whh ready

    // ---- x-part for t=0 ----
    f32x4 aA0 = {0.f,0.f,0.f,0.f}, aA1 = {0.f,0.f,0.f,0.f};
    f32x4 aB0 = {0.f,0.f,0.f,0.f}, aB1 = {0.f,0.f,0.f,0.f};
    {
        bf16x8 ax[4];
        #pragma unroll
        for (int ks = 0; ks < 4; ++ks)
            ax[ks] = cvt_pack(xf[2 * ks], xf[2 * ks + 1]);
        aA0 = MFMA(ax[0], wi0[0], aA0); aB0 = MFMA(ax[0], wi1[0], aB0);
        aA1 = MFMA(ax[1], wi0[1], aA1); aB1 = MFMA(ax[1], wi1[1], aB1);
        aA0 = MFMA(ax[2], wi0[2], aA0); aB0 = MFMA(ax[2], wi1[2], aB0);
        aA1 = MFMA(ax[3], wi0[3], aA1); aB1 = MFMA(ax[3], wi1[3], aB1);
    }

    for (int t = 0; t < T_STEPS; ++t) {
        // prefetch x for t+1 (consumed at this iteration's tail)
        if (t + 1 < T_STEPS) {
            #pragma unroll
            for (int ks = 0; ks < 4; ++ks) {
                const float* xp = x + (size_t)(t + 1) * BATCH * IN
                                + (size_t)(b0 + col) * IN + ks * 32 + quad * 8;
                xf[2 * ks]     = *(const float4*)xp;
                xf[2 * ks + 1] = *(const float4*)(xp + 4);
            }
        }

        // h A-fragments (global -> registers)
        bf16x8 ah[8];
        if (t == 0) {
            #pragma unroll
            for (int ks = 0; ks < 8; ++ks) {
                const float* hp = hx0 + ks * 32 + quad * 8;
                ah[ks] = cvt_pack(*(const float4*)hp, *(const float4*)(hp + 4));
            }
        } else {
            const __bf16* hb = hexg
                + (((size_t)(t & 1) * NGROUP + g) * BWG + col) * HID;
            #pragma unroll
            for (int ks = 0; ks < 8; ++ks)
                ah[ks] = *(const bf16x8*)(hb + ks * 32 + quad * 8);
        }

        // h-part MFMAs (B-frags from LDS)
        #pragma unroll
        for (int ks = 0; ks < 4; ++ks) {
            bf16x8 w0a = *(const bf16x8*)(wl0 + ks * 32);
            bf16x8 w1a = *(const bf16x8*)(wl1 + ks * 32);
            bf16x8 w0b = *(const bf16x8*)(wl0 + (ks + 4) * 32);
            bf16x8 w1b = *(const bf16x8*)(wl1 + (ks + 4) * 32);
            aA0 = MFMA(ah[ks],     w0a, aA0);
            aB0 = MFMA(ah[ks],     w1a, aB0);
            aA1 = MFMA(ah[ks + 4], w0b, aA1);
            aB1 = MFMA(ah[ks + 4], w1b, aB1);
        }
        f32x4 accA = aA0 + aA1;   // i (hf=0) / f (hf=1)
        f32x4 accB = aB0 + aB1;   // g (hf=0) / o (hf=1)

        // elementwise cell (pair lanes c <-> c+8)
        #pragma unroll
        for (int r = 0; r < 4; ++r) {
            float oA = __shfl_xor(accA[r], 8, 64);
            float oB = __shfl_xor(accB[r], 8, 64);
            float iv = (hf ? oA : accA[r]) + bi;
            float fv = (hf ? accA[r] : oA) + bfv;
            float gv = (hf ? oB : accB[r]) + bg;
            float ov = (hf ? accB[r] : oB) + bo;
            float ig = sigmoidf_fast(iv);
            float fg = sigmoidf_fast(fv);
            float gt = tanhf_fast(gv);
            float og = sigmoidf_fast(ov);
            float cn = fg * cst[r] + ig * gt;
            cst[r] = cn;
            hn[r]  = og * tanhf_fast(cn);
        }

        if (t < T_STEPS - 1) {
            // own h slice -> hexg (bf16)
            if (col < 8) {
                __bf16* dst = hexg
                    + (((size_t)((t + 1) & 1) * NGROUP + g) * BWG) * HID + jcol;
                #pragma unroll
                for (int r = 0; r < 4; ++r)
                    dst[(quad * 4 + r) * HID] = (__bf16)hn[r];
            }
            __syncthreads();   // drain all waves' stores to L2

            if (tid == 0)
                __hip_atomic_fetch_add(cntg, 1, __ATOMIC_RELEASE,
                                       __HIP_MEMORY_SCOPE_AGENT);

            // x-part for t+1 (h-independent) overlaps the sync window
            {
                bf16x8 ax[4];
                #pragma unroll
                for (int ks = 0; ks < 4; ++ks)
                    ax[ks] = cvt_pack(xf[2 * ks], xf[2 * ks + 1]);
                aA0 = {0.f,0.f,0.f,0.f}; aA1 = {0.f,0.f,0.f,0.f};
                aB0 = {0.f,0.f,0.f,0.f}; aB1 = {0.f,0.f,0.f,0.f};
                aA0 = MFMA(ax[0], wi0[0], aA0); aB0 = MFMA(ax[0], wi1[0], aB0);
                aA1 = MFMA(ax[1], wi0[1], aA1); aB1 = MFMA(ax[1], wi1[1], aB1);
                aA0 = MFMA(ax[2], wi0[2], aA0); aB0 = MFMA(ax[2], wi1[2], aB0);
                aA1 = MFMA(ax[3], wi0[3], aA1); aB1 = MFMA(ax[3], wi1[3], aB1);
            }

            if (tid == 0) {
                const int target = 4 * (t + 1);
                int guard = 0;
                // relaxed RMW polls execute at the coherence point: fresh,
                // and no per-poll L2 invalidate
                while (__hip_atomic_fetch_add(cntg, 0, __ATOMIC_RELAXED,
                                              __HIP_MEMORY_SCOPE_AGENT) < target) {
                    __builtin_amdgcn_s_sleep(2);
                    if (++guard > (1 << 22)) break;   // fail-fast over deadlock
                }
                (void)__hip_atomic_load(cntg, __ATOMIC_ACQUIRE,
                                        __HIP_MEMORY_SCOPE_AGENT);
            }
            __syncthreads();
        }
    }

    // final h, c
    if (col < 8) {
        #pragma unroll
        for (int r = 0; r < 4; ++r) {
            int row = b0 + quad * 4 + r;
            out[(size_t)row * HID + jcol] = hn[r];
            out[(size_t)BATCH * HID + (size_t)row * HID + jcol] = cst[r];
        }
    }
}

extern "C" void kernel_launch(void* const* d_in, const int* in_sizes, int n_in,
                              void* d_out, int out_size, void* d_ws, size_t ws_size,
                              hipStream_t stream) {
    const float* x    = (const float*)d_in[0];
    const float* W_ih = (const float*)d_in[1];
    const float* W_hh = (const float*)d_in[2];
    const float* b_ih = (const float*)d_in[3];
    const float* b_hh = (const float*)d_in[4];
    const float* hx0  = (const float*)d_in[5];
    const float* cx0  = (const float*)d_in[6];
    float* outp = (float*)d_out;

    __bf16* wcat = (__bf16*)((char*)d_ws + WCAT_OFF);
    float*  bias = (float*)((char*)d_ws + BIAS_OFF);
    __bf16* hexg = (__bf16*)((char*)d_ws + HEXG_OFF);
    int*    cnt  = (int*)((char*)d_ws + CNT_OFF);

    precast_kernel<<<dim3((NG * KTOT + 255) / 256), dim3(256), 0, stream>>>(
        W_ih, W_hh, b_ih, b_hh, wcat, bias, cnt);

    void* args[] = {(void*)&x, (void*)&wcat, (void*)&bias, (void*)&hx0,
                    (void*)&cx0, (void*)&hexg, (void*)&cnt, (void*)&outp};
    hipLaunchCooperativeKernel((const void*)lstm_kernel, dim3(256), dim3(512),
                               args, 0, stream);
}

// Round 4
// 2978.585 us; speedup vs baseline: 1.8260x; 1.8260x over previous
//
#include <hip/hip_runtime.h>
#include <hip/hip_bf16.h>

// LSTM forward: T=512 (511 steps), B=1024, I=128, H=256, 4H=1024.
// Round 4: fence-free inter-wg handshake. All cross-wg traffic uses RELAXED
// agent-scope atomics (sc0/sc1 -> IF$ coherence point, no wbl2/inv), ordered
// by per-wave s_waitcnt vmcnt(0) before a relaxed flag bump. 256 wgs =
// 64 batch groups x 4 hidden slices; W_hh slice LDS-resident, W_ih slice in
// registers; h staged IF$ -> LDS once per wg per step.

#define T_STEPS 511
#define BATCH   1024
#define IN      128
#define HID     256
#define NG      1024
#define KTOT    384
#define BWG     16
#define NGROUP  64
#define SW      264   // LDS W_hh row stride (bf16): 528 B = 33*16, b128-aligned
#define HS      264   // LDS Ah row stride

typedef __bf16 bf16x8 __attribute__((ext_vector_type(8)));
typedef float  f32x4  __attribute__((ext_vector_type(4)));
typedef unsigned long long u64;

// workspace layout (bytes)
#define WCAT_OFF 0
#define BIAS_OFF 786432
#define HEXG_OFF 790528                 // 2*64*16*256 bf16 = 1 MB
#define CNT_OFF  1839104                // 64 groups * 32 ints

__global__ void precast_kernel(const float* __restrict__ W_ih,
                               const float* __restrict__ W_hh,
                               const float* __restrict__ b_ih,
                               const float* __restrict__ b_hh,
                               __bf16* __restrict__ wcat,
                               float* __restrict__ bias,
                               int* __restrict__ cnt) {
    int idx = blockIdx.x * blockDim.x + threadIdx.x;
    if (idx < NG * KTOT) {
        int n = idx / KTOT, k = idx % KTOT;
        float v = (k < IN) ? W_ih[n * IN + k] : W_hh[n * HID + (k - IN)];
        wcat[idx] = (__bf16)v;
    }
    if (idx < NG) bias[idx] = b_ih[idx] + b_hh[idx];
    if (idx < NGROUP * 32) cnt[idx] = 0;
}

__device__ __forceinline__ float sigmoidf_fast(float v) {
    return 1.f / (1.f + __expf(-v));
}
__device__ __forceinline__ float tanhf_fast(float v) {
    return 1.f - 2.f / (1.f + __expf(2.f * v));
}

#define MFMA(a, b, c) __builtin_amdgcn_mfma_f32_16x16x32_bf16((a), (b), (c), 0, 0, 0)

__device__ __forceinline__ bf16x8 cvt_pack(float4 lo, float4 hi) {
    return bf16x8{(__bf16)lo.x, (__bf16)lo.y, (__bf16)lo.z, (__bf16)lo.w,
                  (__bf16)hi.x, (__bf16)hi.y, (__bf16)hi.z, (__bf16)hi.w};
}

__global__ __launch_bounds__(512, 2) void lstm_kernel(
    const float* __restrict__ x,      // (512,1024,128) fp32
    const __bf16* __restrict__ wcat,  // (1024,384) bf16
    const float* __restrict__ bias,   // (1024,)
    const float* __restrict__ hx0,
    const float* __restrict__ cx0,
    __bf16* __restrict__ hexg,        // [2][64][16][256] bf16 (IF$-coherent)
    int* __restrict__ cnt,            // [64][32] int
    float* __restrict__ out)          // h (1024,256), c (1024,256) fp32
{
    __shared__ alignas(16) __bf16 Whh[256 * SW];   // 135168 B
    __shared__ alignas(16) __bf16 Ah[BWG * HS];    //   8448 B

    const int tid  = threadIdx.x;
    const int bx   = blockIdx.x;
    const int g    = bx & 63;          // batch group 0..63
    const int s    = bx >> 6;          // hidden slice 0..3
    const int wave = tid >> 6;
    const int lane = tid & 63;
    const int col  = lane & 15;
    const int quad = lane >> 4;
    const int hf   = col >> 3;         // 0: {i,g} lanes, 1: {f,o} lanes
    const int b0   = g * BWG;
    const int j0   = s * 64;
    const int jcol = j0 + wave * 8 + (col & 7);

    int* cntg = cnt + g * 32;

    // ---- fill LDS W_hh: row r = gate(r>>6)*64 + local col, k=0..255 ----
    {
        int r  = tid >> 1;
        int hh = (tid & 1) * 128;
        int ngl = ((r >> 6) << 8) + j0 + (r & 63);
        const __bf16* src = wcat + (size_t)ngl * KTOT + IN + hh;
        __bf16* dst = &Whh[r * SW + hh];
        #pragma unroll
        for (int i = 0; i < 16; ++i)
            *(bf16x8*)(dst + i * 8) = *(const bf16x8*)(src + i * 8);
    }

    // ---- W_ih fragments in registers: tile0 {i|f}, tile1 {g|o} ----
    const int n0 = (hf ? 256 : 0) + jcol;
    const int n1 = 512 + (hf ? 256 : 0) + jcol;
    bf16x8 wi0[4], wi1[4];
    #pragma unroll
    for (int ks = 0; ks < 4; ++ks) {
        wi0[ks] = *(const bf16x8*)(wcat + (size_t)n0 * KTOT + ks * 32 + quad * 8);
        wi1[ks] = *(const bf16x8*)(wcat + (size_t)n1 * KTOT + ks * 32 + quad * 8);
    }

    const float bi  = bias[jcol];
    const float bfv = bias[256 + jcol];
    const float bg  = bias[512 + jcol];
    const float bo  = bias[768 + jcol];

    float cst[4], hn[4];
    {
        float cv = cx0[jcol];
        #pragma unroll
        for (int r = 0; r < 4; ++r) cst[r] = cv;
    }

    // ---- x[0] (consumed pre-loop) and x[1] (prefetch) ----
    float4 x0f[8], xf[8];
    #pragma unroll
    for (int ks = 0; ks < 4; ++ks) {
        const float* xp = x + (size_t)(b0 + col) * IN + ks * 32 + quad * 8;
        x0f[2 * ks]     = *(const float4*)xp;
        x0f[2 * ks + 1] = *(const float4*)(xp + 4);
        const float* xq = xp + (size_t)BATCH * IN;
        xf[2 * ks]      = *(const float4*)xq;
        xf[2 * ks + 1]  = *(const float4*)(xq + 4);
    }

    // LDS B-frag base pointers
    const int nl0 = hf * 64 + wave * 8 + (col & 7);
    const __bf16* wl0 = &Whh[nl0 * SW + quad * 8];
    const __bf16* wl1 = &Whh[(128 + nl0) * SW + quad * 8];

    __syncthreads();   // Whh ready

    // ---- x-part for t=0 ----
    f32x4 aA0 = {0.f,0.f,0.f,0.f}, aA1 = {0.f,0.f,0.f,0.f};
    f32x4 aB0 = {0.f,0.f,0.f,0.f}, aB1 = {0.f,0.f,0.f,0.f};
    {
        bf16x8 ax[4];
        #pragma unroll
        for (int ks = 0; ks < 4; ++ks)
            ax[ks] = cvt_pack(x0f[2 * ks], x0f[2 * ks + 1]);
        aA0 = MFMA(ax[0], wi0[0], aA0); aB0 = MFMA(ax[0], wi1[0], aB0);
        aA1 = MFMA(ax[1], wi0[1], aA1); aB1 = MFMA(ax[1], wi1[1], aB1);
        aA0 = MFMA(ax[2], wi0[2], aA0); aB0 = MFMA(ax[2], wi1[2], aB0);
        aA1 = MFMA(ax[3], wi0[3], aA1); aB1 = MFMA(ax[3], wi1[3], aB1);
    }

    for (int t = 0; t < T_STEPS; ++t) {
        // ---- A: obtain h_t A-fragments ----
        bf16x8 ahf[8];
        if (t == 0) {
            #pragma unroll
            for (int ks = 0; ks < 8; ++ks) {
                const float* hp = hx0 + ks * 32 + quad * 8;
                ahf[ks] = cvt_pack(*(const float4*)hp, *(const float4*)(hp + 4));
            }
        } else {
            // poll partners' per-wave bumps (relaxed load: no cache inv)
            const int target = 32 * t;
            int guard = 0;
            while (__hip_atomic_load(cntg, __ATOMIC_RELAXED,
                                     __HIP_MEMORY_SCOPE_AGENT) < target) {
                __builtin_amdgcn_s_sleep(1);
                if (++guard > (1 << 22)) break;   // fail-fast over deadlock
            }
            // stage h tile IF$ -> LDS (512 threads x 16 B)
            const u64* sp = (const u64*)(hexg
                + ((size_t)((t & 1) * NGROUP + g)) * (BWG * HID)) + tid * 2;
            u64 v0 = __hip_atomic_load(sp,     __ATOMIC_RELAXED, __HIP_MEMORY_SCOPE_AGENT);
            u64 v1 = __hip_atomic_load(sp + 1, __ATOMIC_RELAXED, __HIP_MEMORY_SCOPE_AGENT);
            int row = tid >> 5, c8 = (tid & 31) * 8;
            *(u64*)&Ah[row * HS + c8]     = v0;
            *(u64*)&Ah[row * HS + c8 + 4] = v1;
            __syncthreads();
            #pragma unroll
            for (int ks = 0; ks < 8; ++ks)
                ahf[ks] = *(const bf16x8*)&Ah[col * HS + ks * 32 + quad * 8];
        }

        // ---- B: h-part MFMAs + cell ----
        #pragma unroll
        for (int ks = 0; ks < 4; ++ks) {
            bf16x8 w0a = *(const bf16x8*)(wl0 + ks * 32);
            bf16x8 w1a = *(const bf16x8*)(wl1 + ks * 32);
            bf16x8 w0b = *(const bf16x8*)(wl0 + (ks + 4) * 32);
            bf16x8 w1b = *(const bf16x8*)(wl1 + (ks + 4) * 32);
            aA0 = MFMA(ahf[ks],     w0a, aA0);
            aB0 = MFMA(ahf[ks],     w1a, aB0);
            aA1 = MFMA(ahf[ks + 4], w0b, aA1);
            aB1 = MFMA(ahf[ks + 4], w1b, aB1);
        }
        f32x4 accA = aA0 + aA1;   // i (hf=0) / f (hf=1)
        f32x4 accB = aB0 + aB1;   // g (hf=0) / o (hf=1)

        #pragma unroll
        for (int r = 0; r < 4; ++r) {
            float oA = __shfl_xor(accA[r], 8, 64);
            float oB = __shfl_xor(accB[r], 8, 64);
            float iv = (hf ? oA : accA[r]) + bi;
            float fv = (hf ? accA[r] : oA) + bfv;
            float gv = (hf ? oB : accB[r]) + bg;
            float ov = (hf ? accB[r] : oB) + bo;
            float ig = sigmoidf_fast(iv);
            float fg = sigmoidf_fast(fv);
            float gt = tanhf_fast(gv);
            float og = sigmoidf_fast(ov);
            float cn = fg * cst[r] + ig * gt;
            cst[r] = cn;
            hn[r]  = og * tanhf_fast(cn);
        }

        // ---- C: publish h_{t+1} (relaxed sc1 stores), drain, bump ----
        if (t < T_STEPS - 1) {
            __bf16* base = hexg
                + ((size_t)((((t + 1) & 1) * NGROUP) + g)) * (BWG * HID);
            #pragma unroll
            for (int r = 0; r < 4; ++r) {
                unsigned short mine;
                {
                    __bf16 hv = (__bf16)hn[r];
                    __builtin_memcpy(&mine, &hv, 2);
                }
                int other = __shfl_xor((int)mine, 1, 64);
                if ((col & 1) == 0 && col < 8) {
                    unsigned int val = (unsigned int)mine
                                     | ((unsigned int)(unsigned short)other << 16);
                    unsigned int* p = (unsigned int*)(base
                        + (size_t)(quad * 4 + r) * HID + jcol);
                    __hip_atomic_store(p, val, __ATOMIC_RELAXED,
                                       __HIP_MEMORY_SCOPE_AGENT);
                }
            }
            // per-wave: my stores are ack'd at the coherence point
            asm volatile("s_waitcnt vmcnt(0)" ::: "memory");
            if (lane == 0)
                __hip_atomic_fetch_add(cntg, 1, __ATOMIC_RELAXED,
                                       __HIP_MEMORY_SCOPE_AGENT);

            // ---- D: x-part for t+1 in the sync shadow ----
            {
                bf16x8 ax[4];
                #pragma unroll
                for (int ks = 0; ks < 4; ++ks)
                    ax[ks] = cvt_pack(xf[2 * ks], xf[2 * ks + 1]);
                aA0 = {0.f,0.f,0.f,0.f}; aA1 = {0.f,0.f,0.f,0.f};
                aB0 = {0.f,0.f,0.f,0.f}; aB1 = {0.f,0.f,0.f,0.f};
                aA0 = MFMA(ax[0], wi0[0], aA0); aB0 = MFMA(ax[0], wi1[0], aB0);
                aA1 = MFMA(ax[1], wi0[1], aA1); aB1 = MFMA(ax[1], wi1[1], aB1);
                aA0 = MFMA(ax[2], wi0[2], aA0); aB0 = MFMA(ax[2], wi1[2], aB0);
                aA1 = MFMA(ax[3], wi0[3], aA1); aB1 = MFMA(ax[3], wi1[3], aB1);
            }
            // prefetch x[t+2]
            if (t + 2 <= T_STEPS - 1) {
                #pragma unroll
                for (int ks = 0; ks < 4; ++ks) {
                    const float* xp = x + (size_t)(t + 2) * BATCH * IN
                                    + (size_t)(b0 + col) * IN + ks * 32 + quad * 8;
                    xf[2 * ks]     = *(const float4*)xp;
                    xf[2 * ks + 1] = *(const float4*)(xp + 4);
                }
            }
        }
    }

    // ---- final h, c ----
    if (col < 8) {
        #pragma unroll
        for (int r = 0; r < 4; ++r) {
            int row = b0 + quad * 4 + r;
            out[(size_t)row * HID + jcol] = hn[r];
            out[(size_t)BATCH * HID + (size_t)row * HID + jcol] = cst[r];
        }
    }
}

extern "C" void kernel_launch(void* const* d_in, const int* in_sizes, int n_in,
                              void* d_out, int out_size, void* d_ws, size_t ws_size,
                              hipStream_t stream) {
    const float* x    = (const float*)d_in[0];
    const float* W_ih = (const float*)d_in[1];
    const float* W_hh = (const float*)d_in[2];
    const float* b_ih = (const float*)d_in[3];
    const float* b_hh = (const float*)d_in[4];
    const float* hx0  = (const float*)d_in[5];
    const float* cx0  = (const float*)d_in[6];
    float* outp = (float*)d_out;

    __bf16* wcat = (__bf16*)((char*)d_ws + WCAT_OFF);
    float*  bias = (float*)((char*)d_ws + BIAS_OFF);
    __bf16* hexg = (__bf16*)((char*)d_ws + HEXG_OFF);
    int*    cnt  = (int*)((char*)d_ws + CNT_OFF);

    precast_kernel<<<dim3((NG * KTOT + 255) / 256), dim3(256), 0, stream>>>(
        W_ih, W_hh, b_ih, b_hh, wcat, bias, cnt);

    void* args[] = {(void*)&x, (void*)&wcat, (void*)&bias, (void*)&hx0,
                    (void*)&cx0, (void*)&hexg, (void*)&cnt, (void*)&outp};
    hipLaunchCooperativeKernel((const void*)lstm_kernel, dim3(256), dim3(512),
                               args, 0, stream);
}